// Round 1
// baseline (473.386 us; speedup 1.0000x reference)
//
#include <hip/hip_runtime.h>
#include <math.h>

// Problem constants (reference: B,H,N,D = 4,8,256,32)
constexpr int B = 4, H = 8, N = 256, D = 32;
constexpr int HD = H * D;  // 256

typedef float nfloat4 __attribute__((ext_vector_type(4)));

// ---------------------------------------------------------------------------
// Kernel 1: edge scores + transpose-staged contiguous edge_out writes.
// One block per (b, j-tile, i): blk = ((b*8 + jt)*N + i), 8192 blocks, 256 thr.
//  - reads E[b,h,i,j0..j0+31,:] for all 8 h (4 KiB contiguous per h)
//  - stages s = q*k*E into LDS [32 j][260 floats] (pad 16B/row: conflict-free)
//  - each wave stores full 1 KiB contiguous rows edge_out[b][j][i][0..255]
//  - logit partials (sum over d) -> logits_ws[b][h][i][j]  (8 MiB workspace)
// ---------------------------------------------------------------------------
__global__ __launch_bounds__(256) void edge_scores(
    const float* __restrict__ q,        // [B,H,N,D]
    const float* __restrict__ k,        // [B,H,N,D]
    const float* __restrict__ E,        // [B,H,N,N,D]
    float* __restrict__ edge_out,       // [B,N,N,H*D]
    float* __restrict__ logits_ws)      // [B,H,N,N]
{
    const int tid = threadIdx.x;
    const int blk = blockIdx.x;         // ((b*8 + jt)*N + i)
    const int i  = blk % N;
    const int jt = (blk / N) & 7;       // j-tile (32 j's each)
    const int b  = blk / (N * 8);
    const int j0 = jt * 32;

    __shared__ float sm[32][260];       // [j_local][h*32+d], +4 floats pad
    __shared__ float lgsm[8][32];       // [h][j_local]

    const int d4 = tid & 7;             // float4 index within d (0..7)
    const int jl = tid >> 3;            // local j (0..31)

    #pragma unroll
    for (int h = 0; h < 8; ++h) {
        const size_t bh = (size_t)(b * H + h);
        const nfloat4* E4 = (const nfloat4*)(E + (((bh * N + (size_t)i) * N) + j0) * (size_t)D);
        const nfloat4* K4 = (const nfloat4*)(k + (bh * N + (size_t)j0) * (size_t)D);
        const nfloat4  q4 = ((const nfloat4*)(q + (bh * N + (size_t)i) * (size_t)D))[d4];

        const nfloat4 e  = __builtin_nontemporal_load(E4 + tid);   // tid = jl*8+d4: 4 KiB/block contiguous
        const nfloat4 kk = K4[jl * 8 + d4];                        // L2-hot
        const nfloat4 s  = q4 * kk * e;

        // transpose-stage: row jl, cols h*32 + d4*4 .. +3
        *(nfloat4*)&sm[jl][h * 32 + d4 * 4] = s;

        // logit partial: reduce over d (4 in-lane + 8-lane shfl tree)
        float p = s.x + s.y + s.z + s.w;
        p += __shfl_xor(p, 1);
        p += __shfl_xor(p, 2);
        p += __shfl_xor(p, 4);
        if (d4 == 0) lgsm[h][jl] = p;
    }
    __syncthreads();

    // logits out: thread t -> (h = t>>5, j_local = t&31); 128B contiguous per 32-lane group
    {
        const int h = tid >> 5, jl2 = tid & 31;
        logits_ws[(((size_t)(b * H + h) * N + i) * N) + j0 + jl2] = lgsm[h][jl2];
    }

    // edge_out: wave w stores rows w*8 .. w*8+7, each 1 KiB fully contiguous
    const int lane = tid & 63, wid = tid >> 6;
    #pragma unroll
    for (int r = 0; r < 8; ++r) {
        const int jlr = wid * 8 + r;
        const int j = j0 + jlr;
        const nfloat4 val = *(const nfloat4*)&sm[jlr][lane * 4];
        nfloat4* dst = (nfloat4*)(edge_out + (((size_t)b * N + j) * N + i) * (size_t)HD) + lane;
        __builtin_nontemporal_store(val, dst);
    }
}

// ---------------------------------------------------------------------------
// Kernel 2: softmax over j + PV. One block per (b,h,i), 256 threads.
// Identical math to the verified fused kernel's phases 2-3.
// ---------------------------------------------------------------------------
__global__ __launch_bounds__(256) void softmax_pv(
    const float* __restrict__ v,          // [B,H,N,D]
    const float* __restrict__ logits_ws,  // [B,H,N,N]
    const float* __restrict__ mask,       // [B,N,N]
    float* __restrict__ out)              // [B,N,H*D]
{
    const int tid = threadIdx.x;
    const int blk = blockIdx.x;           // b*H*N + h*N + i
    const int i = blk % N;
    const int h = (blk / N) % H;
    const int b = blk / (N * H);

    __shared__ float probs[N];
    __shared__ float red[256];
    __shared__ float wred[4];
    __shared__ float wsum[4];

    const size_t bh = (size_t)(b * H + h);

    const float scale = 0.17677669529663687f; // 1/sqrt(32)
    const float l = logits_ws[(bh * N + (size_t)i) * N + tid] * scale
                  + mask[((size_t)b * N + i) * N + tid];
    const int lane = tid & 63, wid = tid >> 6;

    float m = l;
    #pragma unroll
    for (int off = 32; off > 0; off >>= 1) m = fmaxf(m, __shfl_xor(m, off));
    if (lane == 0) wred[wid] = m;
    __syncthreads();
    m = fmaxf(fmaxf(wred[0], wred[1]), fmaxf(wred[2], wred[3]));

    const float ex = __expf(l - m);
    float ssum = ex;
    #pragma unroll
    for (int off = 32; off > 0; off >>= 1) ssum += __shfl_xor(ssum, off);
    if (lane == 0) wsum[wid] = ssum;
    __syncthreads();
    const float denom = wsum[0] + wsum[1] + wsum[2] + wsum[3];
    probs[tid] = ex / denom;
    __syncthreads();

    // out[b,i,h*D+d] = sum_j p[j] * v[b,h,j,d]
    const float* vrow = v + bh * (size_t)(N * D);
    const int d = tid & 31;
    const int g = tid >> 5;   // 0..7
    float acc = 0.f;
    #pragma unroll
    for (int jj = 0; jj < 32; ++jj) {
        const int j = jj * 8 + g;
        acc += probs[j] * vrow[j * D + d];
    }
    red[tid] = acc;
    __syncthreads();
    if (tid < 32) {
        float o = red[tid] + red[32 + tid] + red[64 + tid] + red[96 + tid]
                + red[128 + tid] + red[160 + tid] + red[192 + tid] + red[224 + tid];
        out[(((size_t)b * N + i) * HD) + h * D + tid] = o;
    }
}

// ---------------------------------------------------------------------------
// Fallback: original verified single fused kernel (used if workspace too small)
// ---------------------------------------------------------------------------
__global__ __launch_bounds__(256) void fused_edge_attn(
    const float* __restrict__ q,
    const float* __restrict__ k,
    const float* __restrict__ v,
    const float* __restrict__ E,
    const float* __restrict__ mask,
    float* __restrict__ out,
    float* __restrict__ edge_out)
{
    const int tid = threadIdx.x;
    const int blk = blockIdx.x;
    const int i = blk % N;
    const int h = (blk / N) % H;
    const int b = blk / (N * H);

    __shared__ float logits[N];
    __shared__ float red[256];
    __shared__ float wred[4];
    __shared__ float wsum[4];

    const size_t bh = (size_t)(b * H + h);
    const nfloat4* __restrict__ E4 = (const nfloat4*)(E + (bh * N + (size_t)i) * (size_t)(N * D));
    const nfloat4* __restrict__ K4 = (const nfloat4*)(k + bh * (size_t)(N * D));
    const float*   qrow = q + (bh * N + (size_t)i) * D;

    const int d4 = tid & 7;
    const int jq = tid >> 3;
    const nfloat4 q4 = ((const nfloat4*)qrow)[d4];

    nfloat4* __restrict__ eo_base = (nfloat4*)(edge_out + ((size_t)b * N * N + i) * HD + h * D) + d4;

    #pragma unroll
    for (int iter = 0; iter < 8; ++iter) {
        const int j = iter * 32 + jq;
        const nfloat4 e  = __builtin_nontemporal_load(E4 + j * 8 + d4);
        const nfloat4 kk = K4[j * 8 + d4];
        const nfloat4 s = q4 * kk * e;
        __builtin_nontemporal_store(s, eo_base + (size_t)j * (N * HD / 4));
        float partial = s.x + s.y + s.z + s.w;
        partial += __shfl_xor(partial, 1);
        partial += __shfl_xor(partial, 2);
        partial += __shfl_xor(partial, 4);
        if (d4 == 0) logits[j] = partial;
    }
    __syncthreads();

    const float scale = 0.17677669529663687f;
    const float l = logits[tid] * scale + mask[((size_t)b * N + i) * N + tid];
    const int lane = tid & 63, wid = tid >> 6;

    float m = l;
    #pragma unroll
    for (int off = 32; off > 0; off >>= 1) m = fmaxf(m, __shfl_xor(m, off));
    if (lane == 0) wred[wid] = m;
    __syncthreads();
    m = fmaxf(fmaxf(wred[0], wred[1]), fmaxf(wred[2], wred[3]));

    const float ex = __expf(l - m);
    float ssum = ex;
    #pragma unroll
    for (int off = 32; off > 0; off >>= 1) ssum += __shfl_xor(ssum, off);
    if (lane == 0) wsum[wid] = ssum;
    __syncthreads();
    const float denom = wsum[0] + wsum[1] + wsum[2] + wsum[3];
    logits[tid] = ex / denom;
    __syncthreads();

    const float* vrow = v + bh * (size_t)(N * D);
    const int d = tid & 31;
    const int g = tid >> 5;
    float acc = 0.f;
    #pragma unroll
    for (int jj = 0; jj < 32; ++jj) {
        const int j = jj * 8 + g;
        acc += logits[j] * vrow[j * D + d];
    }
    red[tid] = acc;
    __syncthreads();
    if (tid < 32) {
        float o = red[tid] + red[32 + tid] + red[64 + tid] + red[96 + tid]
                + red[128 + tid] + red[160 + tid] + red[192 + tid] + red[224 + tid];
        out[(((size_t)b * N + i) * HD) + h * D + tid] = o;
    }
}

extern "C" void kernel_launch(void* const* d_in, const int* in_sizes, int n_in,
                              void* d_out, int out_size, void* d_ws, size_t ws_size,
                              hipStream_t stream) {
    const float* q    = (const float*)d_in[0];
    const float* k    = (const float*)d_in[1];
    const float* v    = (const float*)d_in[2];
    const float* E    = (const float*)d_in[3];
    const float* mask = (const float*)d_in[4];

    float* out      = (float*)d_out;                       // [B,N,H*D]
    float* edge_out = out + (size_t)B * N * HD;            // [B,N,N,H*D]

    const size_t logits_bytes = (size_t)B * H * N * N * sizeof(float); // 8 MiB
    if (ws_size >= logits_bytes) {
        float* logits_ws = (float*)d_ws;
        edge_scores<<<B * N * 8, 256, 0, stream>>>(q, k, E, edge_out, logits_ws);
        softmax_pv<<<B * H * N, 256, 0, stream>>>(v, logits_ws, mask, out);
    } else {
        // workspace too small: original verified fused path
        fused_edge_attn<<<B * H * N, 256, 0, stream>>>(q, k, v, E, mask, out, edge_out);
    }
}

// Round 2
// 446.134 us; speedup vs baseline: 1.0611x; 1.0611x over previous
//
#include <hip/hip_runtime.h>
#include <math.h>

// Problem constants (reference: B,H,N,D = 4,8,256,32)
constexpr int B = 4, H = 8, N = 256, D = 32;
constexpr int HD = H * D;  // 256

// Native vector type for nontemporal builtins.
typedef float nfloat4 __attribute__((ext_vector_type(4)));

// LDS-only workgroup barrier: waits for LDS ops (lgkmcnt) but NOT for
// outstanding global/nontemporal stores (vmcnt). All cross-thread deps in
// this kernel are through LDS; per-thread global loads get their own
// compiler-inserted vmcnt waits. This lets the 32KB of nontemporal
// edge_out stores drain in the background under softmax+PV instead of
// being force-drained at every __syncthreads (which emits vmcnt(0)).
__device__ inline void barrier_lds_only() {
    asm volatile("s_waitcnt lgkmcnt(0)\n\ts_barrier" ::: "memory");
}

// One block per (b,h,i). 256 threads. Structure identical to the verified
// 444.6us kernel; only the 5 __syncthreads() are replaced by LDS-only
// barriers.
__global__ __launch_bounds__(256) void fused_edge_attn(
    const float* __restrict__ q,      // [B,H,N,D]
    const float* __restrict__ k,      // [B,H,N,D]
    const float* __restrict__ v,      // [B,H,N,D]
    const float* __restrict__ E,      // [B,H,N,N,D]
    const float* __restrict__ mask,   // [B,N,N]
    float* __restrict__ out,          // [B,N,H*D]
    float* __restrict__ edge_out)     // [B,N,N,H*D]  edge_out[b,j,i,h*D+d] = s[b,h,i,j,d]
{
    const int tid = threadIdx.x;
    const int blk = blockIdx.x;           // b*H*N + h*N + i
    const int i = blk % N;
    const int h = (blk / N) % H;
    const int b = blk / (N * H);

    __shared__ float logits[N];   // reused as probs after phase 2
    __shared__ float red[256];
    __shared__ float wred[4];
    __shared__ float wsum[4];

    const size_t bh = (size_t)(b * H + h);
    const nfloat4* __restrict__ E4 = (const nfloat4*)(E + (bh * N + (size_t)i) * (size_t)(N * D));
    const nfloat4* __restrict__ K4 = (const nfloat4*)(k + bh * (size_t)(N * D));
    const float*   qrow = q + (bh * N + (size_t)i) * D;

    // lane mapping for phase 1: tid = jq*8 + d4 (8 lanes span one j's 128B)
    const int d4 = tid & 7;
    const int jq = tid >> 3;     // 0..31
    const nfloat4 q4 = ((const nfloat4*)qrow)[d4];

    nfloat4* __restrict__ eo_base = (nfloat4*)(edge_out + ((size_t)b * N * N + i) * HD + h * D) + d4;

    #pragma unroll
    for (int iter = 0; iter < 8; ++iter) {
        const int j = iter * 32 + jq;
        const nfloat4 e  = __builtin_nontemporal_load(E4 + j * 8 + d4); // 1KiB contiguous per wave
        const nfloat4 kk = K4[j * 8 + d4];                              // L2-hot, keep cached
        const nfloat4 s = q4 * kk * e;
        // edge_out[b][j][i][h*D + d4*4 ...]: 8 lanes -> aligned 128B line;
        // blocks h=0..7 for same i are 256 apart in blockIdx -> same XCD L2
        // merges the 8 fragments into full lines.
        __builtin_nontemporal_store(s, eo_base + (size_t)j * (N * HD / 4));
        // reduce 4 + 8-lane shuffle -> logit for (i,j)
        float partial = s.x + s.y + s.z + s.w;
        partial += __shfl_xor(partial, 1);
        partial += __shfl_xor(partial, 2);
        partial += __shfl_xor(partial, 4);
        if (d4 == 0) logits[j] = partial;   // each j written exactly once
    }
    barrier_lds_only();   // logits[] is LDS; edge_out stores keep draining

    // ---- Phase 2: softmax over j = 0..255, thread tid owns j = tid ----
    const float scale = 0.17677669529663687f; // 1/sqrt(32)
    const float l = logits[tid] * scale + mask[((size_t)b * N + i) * N + tid];
    const int lane = tid & 63, wid = tid >> 6;

    float m = l;
    #pragma unroll
    for (int off = 32; off > 0; off >>= 1) m = fmaxf(m, __shfl_xor(m, off));
    if (lane == 0) wred[wid] = m;
    barrier_lds_only();
    m = fmaxf(fmaxf(wred[0], wred[1]), fmaxf(wred[2], wred[3]));

    const float ex = __expf(l - m);
    float ssum = ex;
    #pragma unroll
    for (int off = 32; off > 0; off >>= 1) ssum += __shfl_xor(ssum, off);
    if (lane == 0) wsum[wid] = ssum;
    barrier_lds_only();
    const float denom = wsum[0] + wsum[1] + wsum[2] + wsum[3];
    logits[tid] = ex / denom;           // logits[] now holds attention probs
    barrier_lds_only();

    // ---- Phase 3: out[b,i,h*D+d] = sum_j p[j] * v[b,h,j,d] ----
    const float* vrow = v + bh * (size_t)(N * D);
    const int d = tid & 31;
    const int g = tid >> 5;   // 0..7
    float acc = 0.f;
    #pragma unroll
    for (int jj = 0; jj < 32; ++jj) {
        const int j = jj * 8 + g;           // block covers 1KiB contiguous of v per jj
        acc += logits[j] * vrow[j * D + d];
    }
    red[tid] = acc;
    barrier_lds_only();
    if (tid < 32) {
        float o = red[tid] + red[32 + tid] + red[64 + tid] + red[96 + tid]
                + red[128 + tid] + red[160 + tid] + red[192 + tid] + red[224 + tid];
        out[(((size_t)b * N + i) * HD) + h * D + tid] = o;
    }
}

extern "C" void kernel_launch(void* const* d_in, const int* in_sizes, int n_in,
                              void* d_out, int out_size, void* d_ws, size_t ws_size,
                              hipStream_t stream) {
    const float* q    = (const float*)d_in[0];
    const float* k    = (const float*)d_in[1];
    const float* v    = (const float*)d_in[2];
    const float* E    = (const float*)d_in[3];
    const float* mask = (const float*)d_in[4];

    float* out      = (float*)d_out;                       // [B,N,H*D], first 262144 floats
    float* edge_out = out + (size_t)B * N * HD;            // [B,N,N,H*D]

    fused_edge_attn<<<B * H * N, 256, 0, stream>>>(q, k, v, E, mask, out, edge_out);
}